// Round 10
// baseline (42.991 us; speedup 1.0000x reference)
//
#include <hip/hip_runtime.h>
#include <hip/hip_bf16.h>

#define BB 4096
#define SS 128
#define DIMQ 512
#define DIMZ 64
#define HIDV 512

typedef __attribute__((ext_vector_type(8))) short sh8;
typedef __attribute__((ext_vector_type(4))) float f32x4;
typedef __attribute__((ext_vector_type(4))) unsigned short us4;

__device__ inline unsigned short f2bf(float f) {
    unsigned u = __float_as_uint(f);
    return (unsigned short)((u + 0x7fffu + ((u >> 16) & 1u)) >> 16);
}

__device__ __forceinline__ float fast_tanh(float x) {
    float e = __expf(2.0f * x);
    return 1.0f - 2.0f * __builtin_amdgcn_rcpf(e + 1.0f);
}

// Blocks 0..2047: states for batches 2b, 2b+1 (128 threads per row).
// Blocks 2048..2303: prep (W1 transpose->bf16, cvec) -- consumed only by k_gemm.
__global__ __launch_bounds__(256) void k_states_prep(
        const float* __restrict__ u, const float* __restrict__ q0off,
        const float* __restrict__ p0off, const float* __restrict__ q0on,
        const float* __restrict__ p0on, const float* __restrict__ b2,
        const float* __restrict__ W1, const float* __restrict__ z,
        const float* __restrict__ b1,
        unsigned short* __restrict__ Qall, unsigned short* __restrict__ W1qT,
        float* __restrict__ cvec, float* __restrict__ out,
        float* __restrict__ qtraj,
        float R00, float R01, float R10, float R11) {
    if (blockIdx.x >= 2048) {
        // ---- prep path ----
        int pbi = blockIdx.x - 2048;
        __shared__ float tile[32][33];
        int bx = pbi & 15, by = pbi >> 4;
        int k0 = by * 32, n0 = bx * 32;
        int tx = threadIdx.x & 31, tg = threadIdx.x >> 5;
        #pragma unroll
        for (int rr = 0; rr < 4; rr++) {
            int ty = tg * 4 + rr;
            tile[ty][tx] = W1[(size_t)(k0 + ty) * HIDV + n0 + tx];
        }
        __syncthreads();
        #pragma unroll
        for (int rr = 0; rr < 4; rr++) {
            int ty = tg * 4 + rr;
            W1qT[(size_t)(n0 + ty) * DIMQ + k0 + tx] = f2bf(tile[tx][ty]);
        }
        if (pbi < 2) {
            int h = pbi * 256 + threadIdx.x;
            float acc = b1[h];
            #pragma unroll 8
            for (int k = 0; k < DIMZ; k++) acc += z[k] * W1[(size_t)(DIMQ + k) * HIDV + h];
            cvec[h] = acc;
        }
        return;
    }
    // ---- states path ----
    int t = threadIdx.x;
    int half = t >> 7;           // which batch row of the pair
    int tc = t & 127;
    int b = blockIdx.x * 2 + half;
    int j = tc * 4;
    size_t idx = (size_t)b * DIMQ + j;
    float q[4], p[4], qo[4], po[4];
    *(float4*)q  = *(const float4*)(q0off + idx);
    *(float4*)p  = *(const float4*)(p0off + idx);
    *(float4*)qo = *(const float4*)(q0on + idx);
    *(float4*)po = *(const float4*)(p0on + idx);

    float sums[8] = {0, 0, 0, 0, 0, 0, 0, 0};
    us4 w0, w1, w2, w3;
    float q2[4], p2[4];
    #pragma unroll
    for (int c = 0; c < 4; c++) {
        float qq = q[c], pp = p[c];
        sums[0] += qq * qq;
        sums[1] += pp * pp;
        float qf = R00 * qq + R01 * pp;
        float pf = R10 * qq + R11 * pp;
        sums[2] += qf * qf;
        sums[3] += pf * pf;
        w0[c] = f2bf(qq);
        w1[c] = f2bf(qf);
        q2[c] = qo[c]; p2[c] = po[c];
        sums[4] += q2[c] * q2[c];
        sums[5] += p2[c] * p2[c];
        w2[c] = f2bf(q2[c]);
    }
    *(us4*)(Qall + idx) = w0;
    *(us4*)(Qall + (size_t)(BB + b) * DIMQ + j) = w1;
    *(us4*)(Qall + (size_t)(2 * BB + b) * DIMQ + j) = w2;

    const float* ub = u + (size_t)b * SS * DIMQ + j;
    #pragma unroll
    for (int st = 0; st < 10; st++) {
        float uv[4];
        *(float4*)uv = *(const float4*)(ub + (size_t)st * DIMQ);
        #pragma unroll
        for (int c = 0; c < 4; c++) {
            p2[c] = (p2[c] - 0.1f * (0.1f * q2[c]) + 0.1f * (0.1f * uv[c])) * 0.99f;
            q2[c] = q2[c] + 0.1f * p2[c];
        }
    }
    #pragma unroll
    for (int c = 0; c < 4; c++) {
        sums[6] += q2[c] * q2[c];
        sums[7] += p2[c] * p2[c];
        w3[c] = f2bf(q2[c]);
    }
    *(us4*)(Qall + (size_t)(3 * BB + b) * DIMQ + j) = w3;
    *(float4*)(qtraj + idx) = *(float4*)q2;

    __shared__ float red[2][2][8];
    int lane = t & 63, wv = (t >> 6) & 1;
    #pragma unroll
    for (int k = 0; k < 8; k++) {
        float v = sums[k];
        #pragma unroll
        for (int m = 1; m < 64; m <<= 1) v += __shfl_xor(v, m, 64);
        if (lane == 0) red[half][wv][k] = v;
    }
    __syncthreads();
    if (tc < 4) {
        int e = tc;
        float sq = red[half][0][2 * e] + red[half][1][2 * e];
        float sp = red[half][0][2 * e + 1] + red[half][1][2 * e + 1];
        float F = 0.5f * sp + 0.05f * sq + b2[0];
        size_t o = (size_t)b * 2 + (e & 1) + (size_t)(e >> 1) * 2 * BB;
        out[o] = F;  // GEMM atomicAdds V_net partials on top
    }
}

// GEMM: Qall(16384x512 bf16) @ W1qT^T with fused fast_tanh(.+c)*W2 reduce-over-N
// epilogue -> atomicAdd into out. 128x128 tile, 64KB LDS (2 blocks/CU),
// 2-buffer counted-vmcnt pipeline: vmcnt(8) waits only the CURRENT buffer's
// stage; next stage stays in flight across the compute phase (T4).
__global__ __launch_bounds__(256) void k_gemm(
        const unsigned short* __restrict__ Qall, const unsigned short* __restrict__ W1qT,
        const float* __restrict__ cvec, const float* __restrict__ W2,
        float* __restrict__ out) {
    __shared__ __attribute__((aligned(16))) char lds[65536];
    const int t = threadIdx.x;
    const int lane = t & 63;
    const int w = t >> 6;
    const int wr = w >> 1, wc = w & 1;
    const int rowBase = blockIdx.x * 128;
    const int colBase = blockIdx.y * 128;

    f32x4 acc[4][4] = {};

    auto STAGE = [&](int kt, int buf) {   // 8 global_load_lds per thread-call
        char* ldsA = lds + buf * 32768;
        char* ldsB = ldsA + 16384;
        #pragma unroll
        for (int i = 0; i < 4; i++) {
            unsigned chunk = i * 256 + t;      // 0..1023, 16B each
            unsigned r = chunk >> 3;           // row 0..127
            unsigned scb = (chunk & 7) ^ (r & 7);
            const unsigned short* srcA = Qall + (size_t)(rowBase + r) * 512 + (unsigned)kt * 64 + scb * 8;
            __builtin_amdgcn_global_load_lds(
                (const __attribute__((address_space(1))) unsigned int*)(const void*)srcA,
                (__attribute__((address_space(3))) unsigned int*)(void*)(ldsA + chunk * 16), 16, 0, 0);
            const unsigned short* srcB = W1qT + (size_t)(colBase + r) * 512 + (unsigned)kt * 64 + scb * 8;
            __builtin_amdgcn_global_load_lds(
                (const __attribute__((address_space(1))) unsigned int*)(const void*)srcB,
                (__attribute__((address_space(3))) unsigned int*)(void*)(ldsB + chunk * 16), 16, 0, 0);
        }
    };

    STAGE(0, 0);
    STAGE(1, 1);

    for (int kt = 0; kt < 8; kt++) {
        int cur = kt & 1;
        if (kt == 7) asm volatile("s_waitcnt vmcnt(0)" ::: "memory");
        else         asm volatile("s_waitcnt vmcnt(8)" ::: "memory");  // stage kt landed; kt+1 in flight
        __builtin_amdgcn_s_barrier();

        char* ldsA = lds + cur * 32768;
        char* ldsB = ldsA + 16384;
        #pragma unroll
        for (int ks = 0; ks < 2; ks++) {
            sh8 af[4], bf_[4];
            int kb = ks * 64 + ((lane >> 4) << 4);
            #pragma unroll
            for (int mi = 0; mi < 4; mi++) {
                int m = wr * 64 + mi * 16 + (lane & 15);
                af[mi] = *(const sh8*)(ldsA + m * 128 + (kb ^ ((m & 7) << 4)));
            }
            #pragma unroll
            for (int ni = 0; ni < 4; ni++) {
                int n = wc * 64 + ni * 16 + (lane & 15);
                bf_[ni] = *(const sh8*)(ldsB + n * 128 + (kb ^ ((n & 7) << 4)));
            }
            #pragma unroll
            for (int mi = 0; mi < 4; mi++)
                #pragma unroll
                for (int ni = 0; ni < 4; ni++)
                    acc[mi][ni] = __builtin_amdgcn_mfma_f32_16x16x32_bf16(af[mi], bf_[ni], acc[mi][ni], 0, 0, 0);
        }
        asm volatile("s_waitcnt lgkmcnt(0)" ::: "memory");   // all own ds_reads of buf[cur] retired
        __builtin_amdgcn_s_barrier();                        // ... across all waves
        if (kt < 6) STAGE(kt + 2, cur);                      // safe overwrite; lands during kt+1
    }

    // epilogue: out[row] += sum_n fast_tanh(acc + c[n]) * W2[n]
    float w2v[4], cv[4];
    #pragma unroll
    for (int ni = 0; ni < 4; ni++) {
        int n = colBase + wc * 64 + ni * 16 + (lane & 15);
        w2v[ni] = W2[n];
        cv[ni] = cvec[n];
    }
    #pragma unroll
    for (int mi = 0; mi < 4; mi++) {
        #pragma unroll
        for (int r = 0; r < 4; r++) {
            float partial = 0.f;
            #pragma unroll
            for (int ni = 0; ni < 4; ni++)
                partial += fast_tanh(acc[mi][ni][r] + cv[ni]) * w2v[ni];
            partial += __shfl_xor(partial, 1, 64);
            partial += __shfl_xor(partial, 2, 64);
            partial += __shfl_xor(partial, 4, 64);
            partial += __shfl_xor(partial, 8, 64);
            if ((lane & 15) == 0) {
                int row = rowBase + wr * 64 + mi * 16 + ((lane >> 4) << 2) + r;
                int e = row >> 12, bb = row & 4095;
                size_t o = (size_t)bb * 2 + (e & 1) + (size_t)(e >> 1) * 2 * BB;
                atomicAdd(out + o, partial);
            }
        }
    }
}

extern "C" void kernel_launch(void* const* d_in, const int* in_sizes, int n_in,
                              void* d_out, int out_size, void* d_ws, size_t ws_size,
                              hipStream_t stream) {
    const float* u     = (const float*)d_in[0];
    const float* q0off = (const float*)d_in[1];
    const float* p0off = (const float*)d_in[2];
    const float* q0on  = (const float*)d_in[3];
    const float* p0on  = (const float*)d_in[4];
    const float* z     = (const float*)d_in[5];
    const float* W1    = (const float*)d_in[6];
    const float* b1    = (const float*)d_in[7];
    const float* W2    = (const float*)d_in[8];
    const float* b2    = (const float*)d_in[9];
    float* out = (float*)d_out;

    char* ws = (char*)d_ws;
    unsigned short* Qall = (unsigned short*)ws;                // 16 MB
    unsigned short* W1qT = (unsigned short*)(ws + 16777216);   // 512 KB
    float* cvec = (float*)(ws + 16777216 + 524288);            // 2 KB

    // offline propagator M^19 (double): q' = q + 0.1 p ; p' = 0.99 p - 0.0099 q
    double a00 = 1, a01 = 0, a10 = 0, a11 = 1;
    const double m00 = 1.0, m01 = 0.1, m10 = -0.1 * 0.1 * 0.99, m11 = 0.99;
    for (int i = 0; i < 19; i++) {
        double n00 = m00 * a00 + m01 * a10;
        double n01 = m00 * a01 + m01 * a11;
        double n10 = m10 * a00 + m11 * a10;
        double n11 = m10 * a01 + m11 * a11;
        a00 = n00; a01 = n01; a10 = n10; a11 = n11;
    }

    k_states_prep<<<2304, 256, 0, stream>>>(u, q0off, p0off, q0on, p0on, b2,
                                            W1, z, b1, Qall, W1qT, cvec, out,
                                            out + 4 * BB,
                                            (float)a00, (float)a01, (float)a10, (float)a11);
    k_gemm<<<dim3(128, 4), 256, 0, stream>>>(Qall, W1qT, cvec, W2, out);
}

// Round 11
// 41.213 us; speedup vs baseline: 1.0431x; 1.0431x over previous
//
#include <hip/hip_runtime.h>
#include <hip/hip_bf16.h>

#define BB 4096
#define SS 128
#define DIMQ 512
#define DIMZ 64
#define HIDV 512

typedef __attribute__((ext_vector_type(8))) short sh8;
typedef __attribute__((ext_vector_type(4))) float f32x4;
typedef __attribute__((ext_vector_type(4))) unsigned short us4;

__device__ inline unsigned short f2bf(float f) {
    unsigned u = __float_as_uint(f);
    return (unsigned short)((u + 0x7fffu + ((u >> 16) & 1u)) >> 16);
}

__device__ __forceinline__ float fast_tanh(float x) {
    float e = __expf(2.0f * x);
    return 1.0f - 2.0f * __builtin_amdgcn_rcpf(e + 1.0f);
}

// Blocks 0..2047: states for batches 2b, 2b+1 (128 threads per row).
// Blocks 2048..2303: prep (W1 transpose->bf16, cvec) -- consumed only by k_gemm.
__global__ __launch_bounds__(256) void k_states_prep(
        const float* __restrict__ u, const float* __restrict__ q0off,
        const float* __restrict__ p0off, const float* __restrict__ q0on,
        const float* __restrict__ p0on, const float* __restrict__ b2,
        const float* __restrict__ W1, const float* __restrict__ z,
        const float* __restrict__ b1,
        unsigned short* __restrict__ Qall, unsigned short* __restrict__ W1qT,
        float* __restrict__ cvec, float* __restrict__ out,
        float* __restrict__ qtraj,
        float R00, float R01, float R10, float R11) {
    if (blockIdx.x >= 2048) {
        // ---- prep path ----
        int pbi = blockIdx.x - 2048;
        __shared__ float tile[32][33];
        int bx = pbi & 15, by = pbi >> 4;
        int k0 = by * 32, n0 = bx * 32;
        int tx = threadIdx.x & 31, tg = threadIdx.x >> 5;
        #pragma unroll
        for (int rr = 0; rr < 4; rr++) {
            int ty = tg * 4 + rr;
            tile[ty][tx] = W1[(size_t)(k0 + ty) * HIDV + n0 + tx];
        }
        __syncthreads();
        #pragma unroll
        for (int rr = 0; rr < 4; rr++) {
            int ty = tg * 4 + rr;
            W1qT[(size_t)(n0 + ty) * DIMQ + k0 + tx] = f2bf(tile[tx][ty]);
        }
        if (pbi < 2) {
            int h = pbi * 256 + threadIdx.x;
            float acc = b1[h];
            #pragma unroll 8
            for (int k = 0; k < DIMZ; k++) acc += z[k] * W1[(size_t)(DIMQ + k) * HIDV + h];
            cvec[h] = acc;
        }
        return;
    }
    // ---- states path ----
    int t = threadIdx.x;
    int half = t >> 7;           // which batch row of the pair
    int tc = t & 127;
    int b = blockIdx.x * 2 + half;
    int j = tc * 4;
    size_t idx = (size_t)b * DIMQ + j;
    float q[4], p[4], qo[4], po[4];
    *(float4*)q  = *(const float4*)(q0off + idx);
    *(float4*)p  = *(const float4*)(p0off + idx);
    *(float4*)qo = *(const float4*)(q0on + idx);
    *(float4*)po = *(const float4*)(p0on + idx);

    float sums[8] = {0, 0, 0, 0, 0, 0, 0, 0};
    us4 w0, w1, w2, w3;
    float q2[4], p2[4];
    #pragma unroll
    for (int c = 0; c < 4; c++) {
        float qq = q[c], pp = p[c];
        sums[0] += qq * qq;
        sums[1] += pp * pp;
        float qf = R00 * qq + R01 * pp;
        float pf = R10 * qq + R11 * pp;
        sums[2] += qf * qf;
        sums[3] += pf * pf;
        w0[c] = f2bf(qq);
        w1[c] = f2bf(qf);
        q2[c] = qo[c]; p2[c] = po[c];
        sums[4] += q2[c] * q2[c];
        sums[5] += p2[c] * p2[c];
        w2[c] = f2bf(q2[c]);
    }
    *(us4*)(Qall + idx) = w0;
    *(us4*)(Qall + (size_t)(BB + b) * DIMQ + j) = w1;
    *(us4*)(Qall + (size_t)(2 * BB + b) * DIMQ + j) = w2;

    const float* ub = u + (size_t)b * SS * DIMQ + j;
    #pragma unroll
    for (int st = 0; st < 10; st++) {
        float uv[4];
        *(float4*)uv = *(const float4*)(ub + (size_t)st * DIMQ);
        #pragma unroll
        for (int c = 0; c < 4; c++) {
            p2[c] = (p2[c] - 0.1f * (0.1f * q2[c]) + 0.1f * (0.1f * uv[c])) * 0.99f;
            q2[c] = q2[c] + 0.1f * p2[c];
        }
    }
    #pragma unroll
    for (int c = 0; c < 4; c++) {
        sums[6] += q2[c] * q2[c];
        sums[7] += p2[c] * p2[c];
        w3[c] = f2bf(q2[c]);
    }
    *(us4*)(Qall + (size_t)(3 * BB + b) * DIMQ + j) = w3;
    *(float4*)(qtraj + idx) = *(float4*)q2;

    __shared__ float red[2][2][8];
    int lane = t & 63, wv = (t >> 6) & 1;
    #pragma unroll
    for (int k = 0; k < 8; k++) {
        float v = sums[k];
        #pragma unroll
        for (int m = 1; m < 64; m <<= 1) v += __shfl_xor(v, m, 64);
        if (lane == 0) red[half][wv][k] = v;
    }
    __syncthreads();
    if (tc < 4) {
        int e = tc;
        float sq = red[half][0][2 * e] + red[half][1][2 * e];
        float sp = red[half][0][2 * e + 1] + red[half][1][2 * e + 1];
        float F = 0.5f * sp + 0.05f * sq + b2[0];
        size_t o = (size_t)b * 2 + (e & 1) + (size_t)(e >> 1) * 2 * BB;
        out[o] = F;  // GEMM atomicAdds V_net partials on top
    }
}

// GEMM: Qall(16384x512 bf16) @ W1qT^T with fused fast_tanh(.+c)*W2 reduce-over-N
// epilogue -> atomicAdd into out. 128x128 tile, R9-champion 2-buffer loop.
// XCD-swizzled block mapping: the 4 col-blocks of a row-tile share bid%8 ->
// same XCD L2, so A-slab re-reads are L2 hits instead of cross-XCD L3.
__global__ __launch_bounds__(256) void k_gemm(
        const unsigned short* __restrict__ Qall, const unsigned short* __restrict__ W1qT,
        const float* __restrict__ cvec, const float* __restrict__ W2,
        float* __restrict__ out) {
    __shared__ __attribute__((aligned(16))) char lds[65536];
    const int t = threadIdx.x;
    const int lane = t & 63;
    const int w = t >> 6;
    const int wr = w >> 1, wc = w & 1;
    const int bid = blockIdx.x;
    const int X = bid & 7, i2 = bid >> 3;
    const int rowBase = (X + 8 * (i2 >> 2)) * 128;
    const int colBase = (i2 & 3) * 128;

    f32x4 acc[4][4] = {};

    auto STAGE = [&](int kt, int buf) {
        char* ldsA = lds + buf * 32768;
        char* ldsB = ldsA + 16384;
        #pragma unroll
        for (int i = 0; i < 4; i++) {
            unsigned chunk = i * 256 + t;      // 0..1023, 16B each
            unsigned r = chunk >> 3;           // row 0..127
            unsigned scb = (chunk & 7) ^ (r & 7);
            const unsigned short* srcA = Qall + (size_t)(rowBase + r) * 512 + (unsigned)kt * 64 + scb * 8;
            __builtin_amdgcn_global_load_lds(
                (const __attribute__((address_space(1))) unsigned int*)(const void*)srcA,
                (__attribute__((address_space(3))) unsigned int*)(void*)(ldsA + chunk * 16), 16, 0, 0);
            const unsigned short* srcB = W1qT + (size_t)(colBase + r) * 512 + (unsigned)kt * 64 + scb * 8;
            __builtin_amdgcn_global_load_lds(
                (const __attribute__((address_space(1))) unsigned int*)(const void*)srcB,
                (__attribute__((address_space(3))) unsigned int*)(void*)(ldsB + chunk * 16), 16, 0, 0);
        }
    };

    STAGE(0, 0);
    asm volatile("s_waitcnt vmcnt(0)" ::: "memory");
    __builtin_amdgcn_s_barrier();

    for (int kt = 0; kt < 8; kt++) {
        int cur = kt & 1;
        if (kt < 7) STAGE(kt + 1, cur ^ 1);
        char* ldsA = lds + cur * 32768;
        char* ldsB = ldsA + 16384;
        #pragma unroll
        for (int ks = 0; ks < 2; ks++) {
            sh8 af[4], bf_[4];
            int kb = ks * 64 + ((lane >> 4) << 4);
            #pragma unroll
            for (int mi = 0; mi < 4; mi++) {
                int m = wr * 64 + mi * 16 + (lane & 15);
                af[mi] = *(const sh8*)(ldsA + m * 128 + (kb ^ ((m & 7) << 4)));
            }
            #pragma unroll
            for (int ni = 0; ni < 4; ni++) {
                int n = wc * 64 + ni * 16 + (lane & 15);
                bf_[ni] = *(const sh8*)(ldsB + n * 128 + (kb ^ ((n & 7) << 4)));
            }
            #pragma unroll
            for (int mi = 0; mi < 4; mi++)
                #pragma unroll
                for (int ni = 0; ni < 4; ni++)
                    acc[mi][ni] = __builtin_amdgcn_mfma_f32_16x16x32_bf16(af[mi], bf_[ni], acc[mi][ni], 0, 0, 0);
        }
        asm volatile("s_waitcnt vmcnt(0) lgkmcnt(0)" ::: "memory");
        __builtin_amdgcn_s_barrier();
    }

    // epilogue: out[row] += sum_n fast_tanh(acc + c[n]) * W2[n]
    float w2v[4], cv[4];
    #pragma unroll
    for (int ni = 0; ni < 4; ni++) {
        int n = colBase + wc * 64 + ni * 16 + (lane & 15);
        w2v[ni] = W2[n];
        cv[ni] = cvec[n];
    }
    #pragma unroll
    for (int mi = 0; mi < 4; mi++) {
        #pragma unroll
        for (int r = 0; r < 4; r++) {
            float partial = 0.f;
            #pragma unroll
            for (int ni = 0; ni < 4; ni++)
                partial += fast_tanh(acc[mi][ni][r] + cv[ni]) * w2v[ni];
            partial += __shfl_xor(partial, 1, 64);
            partial += __shfl_xor(partial, 2, 64);
            partial += __shfl_xor(partial, 4, 64);
            partial += __shfl_xor(partial, 8, 64);
            if ((lane & 15) == 0) {
                int row = rowBase + wr * 64 + mi * 16 + ((lane >> 4) << 2) + r;
                int e = row >> 12, bb = row & 4095;
                size_t o = (size_t)bb * 2 + (e & 1) + (size_t)(e >> 1) * 2 * BB;
                atomicAdd(out + o, partial);
            }
        }
    }
}

extern "C" void kernel_launch(void* const* d_in, const int* in_sizes, int n_in,
                              void* d_out, int out_size, void* d_ws, size_t ws_size,
                              hipStream_t stream) {
    const float* u     = (const float*)d_in[0];
    const float* q0off = (const float*)d_in[1];
    const float* p0off = (const float*)d_in[2];
    const float* q0on  = (const float*)d_in[3];
    const float* p0on  = (const float*)d_in[4];
    const float* z     = (const float*)d_in[5];
    const float* W1    = (const float*)d_in[6];
    const float* b1    = (const float*)d_in[7];
    const float* W2    = (const float*)d_in[8];
    const float* b2    = (const float*)d_in[9];
    float* out = (float*)d_out;

    char* ws = (char*)d_ws;
    unsigned short* Qall = (unsigned short*)ws;                // 16 MB
    unsigned short* W1qT = (unsigned short*)(ws + 16777216);   // 512 KB
    float* cvec = (float*)(ws + 16777216 + 524288);            // 2 KB

    // offline propagator M^19 (double): q' = q + 0.1 p ; p' = 0.99 p - 0.0099 q
    double a00 = 1, a01 = 0, a10 = 0, a11 = 1;
    const double m00 = 1.0, m01 = 0.1, m10 = -0.1 * 0.1 * 0.99, m11 = 0.99;
    for (int i = 0; i < 19; i++) {
        double n00 = m00 * a00 + m01 * a10;
        double n01 = m00 * a01 + m01 * a11;
        double n10 = m10 * a00 + m11 * a10;
        double n11 = m10 * a01 + m11 * a11;
        a00 = n00; a01 = n01; a10 = n10; a11 = n11;
    }

    k_states_prep<<<2304, 256, 0, stream>>>(u, q0off, p0off, q0on, p0on, b2,
                                            W1, z, b1, Qall, W1qT, cvec, out,
                                            out + 4 * BB,
                                            (float)a00, (float)a01, (float)a10, (float)a11);
    k_gemm<<<512, 256, 0, stream>>>(Qall, W1qT, cvec, W2, out);
}

// Round 12
// 40.616 us; speedup vs baseline: 1.0585x; 1.0147x over previous
//
#include <hip/hip_runtime.h>
#include <hip/hip_bf16.h>

#define BB 4096
#define SS 128
#define DIMQ 512
#define DIMZ 64
#define HIDV 512

typedef __attribute__((ext_vector_type(8))) short sh8;
typedef __attribute__((ext_vector_type(4))) float f32x4;
typedef __attribute__((ext_vector_type(4))) unsigned short us4;

__device__ inline unsigned short f2bf(float f) {
    unsigned u = __float_as_uint(f);
    return (unsigned short)((u + 0x7fffu + ((u >> 16) & 1u)) >> 16);
}

__device__ __forceinline__ float fast_tanh(float x) {
    float e = __expf(2.0f * x);
    return 1.0f - 2.0f * __builtin_amdgcn_rcpf(e + 1.0f);
}

// Blocks 0..2047: states. Batch mapping is XCD-aware: batch chunk c=b>>7 is
// handled by scan blocks on XCD c&7 -- the SAME XCD the gemm's swizzle assigns
// row-tile c to, so Qall producer L2 == consumer L2 (no cross-XCD dirty reads).
// Blocks 2048..2303: prep (W1 transpose->bf16, cvec) -- consumed only by k_gemm.
__global__ __launch_bounds__(256) void k_states_prep(
        const float* __restrict__ u, const float* __restrict__ q0off,
        const float* __restrict__ p0off, const float* __restrict__ q0on,
        const float* __restrict__ p0on, const float* __restrict__ b2,
        const float* __restrict__ W1, const float* __restrict__ z,
        const float* __restrict__ b1,
        unsigned short* __restrict__ Qall, unsigned short* __restrict__ W1qT,
        float* __restrict__ cvec, float* __restrict__ out,
        float* __restrict__ qtraj,
        float R00, float R01, float R10, float R11) {
    if (blockIdx.x >= 2048) {
        // ---- prep path ----
        int pbi = blockIdx.x - 2048;
        __shared__ float tile[32][33];
        int bx = pbi & 15, by = pbi >> 4;
        int k0 = by * 32, n0 = bx * 32;
        int tx = threadIdx.x & 31, tg = threadIdx.x >> 5;
        #pragma unroll
        for (int rr = 0; rr < 4; rr++) {
            int ty = tg * 4 + rr;
            tile[ty][tx] = W1[(size_t)(k0 + ty) * HIDV + n0 + tx];
        }
        __syncthreads();
        #pragma unroll
        for (int rr = 0; rr < 4; rr++) {
            int ty = tg * 4 + rr;
            W1qT[(size_t)(n0 + ty) * DIMQ + k0 + tx] = f2bf(tile[tx][ty]);
        }
        if (pbi < 2) {
            int h = pbi * 256 + threadIdx.x;
            float acc = b1[h];
            #pragma unroll 8
            for (int k = 0; k < DIMZ; k++) acc += z[k] * W1[(size_t)(DIMQ + k) * HIDV + h];
            cvec[h] = acc;
        }
        return;
    }
    // ---- states path ----
    int t = threadIdx.x;
    int half = t >> 7;           // which batch row of the pair
    int tc = t & 127;
    // XCD-aware batch assignment: s = x + 8m; chunk = x + 8*(m>>6)
    int s = blockIdx.x;
    int x = s & 7, m = s >> 3;
    int b = (x + 8 * (m >> 6)) * 128 + (m & 63) * 2 + half;
    int j = tc * 4;
    size_t idx = (size_t)b * DIMQ + j;
    float q[4], p[4], qo[4], po[4];
    *(float4*)q  = *(const float4*)(q0off + idx);
    *(float4*)p  = *(const float4*)(p0off + idx);
    *(float4*)qo = *(const float4*)(q0on + idx);
    *(float4*)po = *(const float4*)(p0on + idx);

    float sums[8] = {0, 0, 0, 0, 0, 0, 0, 0};
    us4 w0, w1, w2, w3;
    float q2[4], p2[4];
    #pragma unroll
    for (int c = 0; c < 4; c++) {
        float qq = q[c], pp = p[c];
        sums[0] += qq * qq;
        sums[1] += pp * pp;
        float qf = R00 * qq + R01 * pp;
        float pf = R10 * qq + R11 * pp;
        sums[2] += qf * qf;
        sums[3] += pf * pf;
        w0[c] = f2bf(qq);
        w1[c] = f2bf(qf);
        q2[c] = qo[c]; p2[c] = po[c];
        sums[4] += q2[c] * q2[c];
        sums[5] += p2[c] * p2[c];
        w2[c] = f2bf(q2[c]);
    }
    *(us4*)(Qall + idx) = w0;
    *(us4*)(Qall + (size_t)(BB + b) * DIMQ + j) = w1;
    *(us4*)(Qall + (size_t)(2 * BB + b) * DIMQ + j) = w2;

    const float* ub = u + (size_t)b * SS * DIMQ + j;
    #pragma unroll
    for (int st = 0; st < 10; st++) {
        float uv[4];
        *(float4*)uv = *(const float4*)(ub + (size_t)st * DIMQ);
        #pragma unroll
        for (int c = 0; c < 4; c++) {
            p2[c] = (p2[c] - 0.1f * (0.1f * q2[c]) + 0.1f * (0.1f * uv[c])) * 0.99f;
            q2[c] = q2[c] + 0.1f * p2[c];
        }
    }
    #pragma unroll
    for (int c = 0; c < 4; c++) {
        sums[6] += q2[c] * q2[c];
        sums[7] += p2[c] * p2[c];
        w3[c] = f2bf(q2[c]);
    }
    *(us4*)(Qall + (size_t)(3 * BB + b) * DIMQ + j) = w3;
    *(float4*)(qtraj + idx) = *(float4*)q2;

    __shared__ float red[2][2][8];
    int lane = t & 63, wv = (t >> 6) & 1;
    #pragma unroll
    for (int k = 0; k < 8; k++) {
        float v = sums[k];
        #pragma unroll
        for (int mm = 1; mm < 64; mm <<= 1) v += __shfl_xor(v, mm, 64);
        if (lane == 0) red[half][wv][k] = v;
    }
    __syncthreads();
    if (tc < 4) {
        int e = tc;
        float sq = red[half][0][2 * e] + red[half][1][2 * e];
        float sp = red[half][0][2 * e + 1] + red[half][1][2 * e + 1];
        float F = 0.5f * sp + 0.05f * sq + b2[0];
        size_t o = (size_t)b * 2 + (e & 1) + (size_t)(e >> 1) * 2 * BB;
        out[o] = F;  // GEMM atomicAdds V_net partials on top
    }
}

// GEMM: Qall(16384x512 bf16) @ W1qT^T with fused fast_tanh(.+c)*W2 reduce-over-N
// epilogue -> atomicAdd into out. 128x128 tile, R9-champion 2-buffer loop.
// XCD-swizzled block mapping: rowTile = X + 8*(i2>>2) with X = bid&7 = XCD;
// the 4 col-blocks of a row-tile share the XCD, and (this round) the scan
// produced that row-tile's Qall rows on the same XCD.
__global__ __launch_bounds__(256) void k_gemm(
        const unsigned short* __restrict__ Qall, const unsigned short* __restrict__ W1qT,
        const float* __restrict__ cvec, const float* __restrict__ W2,
        float* __restrict__ out) {
    __shared__ __attribute__((aligned(16))) char lds[65536];
    const int t = threadIdx.x;
    const int lane = t & 63;
    const int w = t >> 6;
    const int wr = w >> 1, wc = w & 1;
    const int bid = blockIdx.x;
    const int X = bid & 7, i2 = bid >> 3;
    const int rowBase = (X + 8 * (i2 >> 2)) * 128;
    const int colBase = (i2 & 3) * 128;

    f32x4 acc[4][4] = {};

    auto STAGE = [&](int kt, int buf) {
        char* ldsA = lds + buf * 32768;
        char* ldsB = ldsA + 16384;
        #pragma unroll
        for (int i = 0; i < 4; i++) {
            unsigned chunk = i * 256 + t;      // 0..1023, 16B each
            unsigned r = chunk >> 3;           // row 0..127
            unsigned scb = (chunk & 7) ^ (r & 7);
            const unsigned short* srcA = Qall + (size_t)(rowBase + r) * 512 + (unsigned)kt * 64 + scb * 8;
            __builtin_amdgcn_global_load_lds(
                (const __attribute__((address_space(1))) unsigned int*)(const void*)srcA,
                (__attribute__((address_space(3))) unsigned int*)(void*)(ldsA + chunk * 16), 16, 0, 0);
            const unsigned short* srcB = W1qT + (size_t)(colBase + r) * 512 + (unsigned)kt * 64 + scb * 8;
            __builtin_amdgcn_global_load_lds(
                (const __attribute__((address_space(1))) unsigned int*)(const void*)srcB,
                (__attribute__((address_space(3))) unsigned int*)(void*)(ldsB + chunk * 16), 16, 0, 0);
        }
    };

    STAGE(0, 0);
    asm volatile("s_waitcnt vmcnt(0)" ::: "memory");
    __builtin_amdgcn_s_barrier();

    for (int kt = 0; kt < 8; kt++) {
        int cur = kt & 1;
        if (kt < 7) STAGE(kt + 1, cur ^ 1);
        char* ldsA = lds + cur * 32768;
        char* ldsB = ldsA + 16384;
        #pragma unroll
        for (int ks = 0; ks < 2; ks++) {
            sh8 af[4], bf_[4];
            int kb = ks * 64 + ((lane >> 4) << 4);
            #pragma unroll
            for (int mi = 0; mi < 4; mi++) {
                int m = wr * 64 + mi * 16 + (lane & 15);
                af[mi] = *(const sh8*)(ldsA + m * 128 + (kb ^ ((m & 7) << 4)));
            }
            #pragma unroll
            for (int ni = 0; ni < 4; ni++) {
                int n = wc * 64 + ni * 16 + (lane & 15);
                bf_[ni] = *(const sh8*)(ldsB + n * 128 + (kb ^ ((n & 7) << 4)));
            }
            #pragma unroll
            for (int mi = 0; mi < 4; mi++)
                #pragma unroll
                for (int ni = 0; ni < 4; ni++)
                    acc[mi][ni] = __builtin_amdgcn_mfma_f32_16x16x32_bf16(af[mi], bf_[ni], acc[mi][ni], 0, 0, 0);
        }
        asm volatile("s_waitcnt vmcnt(0) lgkmcnt(0)" ::: "memory");
        __builtin_amdgcn_s_barrier();
    }

    // epilogue: out[row] += sum_n fast_tanh(acc + c[n]) * W2[n]
    float w2v[4], cv[4];
    #pragma unroll
    for (int ni = 0; ni < 4; ni++) {
        int n = colBase + wc * 64 + ni * 16 + (lane & 15);
        w2v[ni] = W2[n];
        cv[ni] = cvec[n];
    }
    #pragma unroll
    for (int mi = 0; mi < 4; mi++) {
        #pragma unroll
        for (int r = 0; r < 4; r++) {
            float partial = 0.f;
            #pragma unroll
            for (int ni = 0; ni < 4; ni++)
                partial += fast_tanh(acc[mi][ni][r] + cv[ni]) * w2v[ni];
            partial += __shfl_xor(partial, 1, 64);
            partial += __shfl_xor(partial, 2, 64);
            partial += __shfl_xor(partial, 4, 64);
            partial += __shfl_xor(partial, 8, 64);
            if ((lane & 15) == 0) {
                int row = rowBase + wr * 64 + mi * 16 + ((lane >> 4) << 2) + r;
                int e = row >> 12, bb = row & 4095;
                size_t o = (size_t)bb * 2 + (e & 1) + (size_t)(e >> 1) * 2 * BB;
                atomicAdd(out + o, partial);
            }
        }
    }
}

extern "C" void kernel_launch(void* const* d_in, const int* in_sizes, int n_in,
                              void* d_out, int out_size, void* d_ws, size_t ws_size,
                              hipStream_t stream) {
    const float* u     = (const float*)d_in[0];
    const float* q0off = (const float*)d_in[1];
    const float* p0off = (const float*)d_in[2];
    const float* q0on  = (const float*)d_in[3];
    const float* p0on  = (const float*)d_in[4];
    const float* z     = (const float*)d_in[5];
    const float* W1    = (const float*)d_in[6];
    const float* b1    = (const float*)d_in[7];
    const float* W2    = (const float*)d_in[8];
    const float* b2    = (const float*)d_in[9];
    float* out = (float*)d_out;

    char* ws = (char*)d_ws;
    unsigned short* Qall = (unsigned short*)ws;                // 16 MB
    unsigned short* W1qT = (unsigned short*)(ws + 16777216);   // 512 KB
    float* cvec = (float*)(ws + 16777216 + 524288);            // 2 KB

    // offline propagator M^19 (double): q' = q + 0.1 p ; p' = 0.99 p - 0.0099 q
    double a00 = 1, a01 = 0, a10 = 0, a11 = 1;
    const double m00 = 1.0, m01 = 0.1, m10 = -0.1 * 0.1 * 0.99, m11 = 0.99;
    for (int i = 0; i < 19; i++) {
        double n00 = m00 * a00 + m01 * a10;
        double n01 = m00 * a01 + m01 * a11;
        double n10 = m10 * a00 + m11 * a10;
        double n11 = m10 * a01 + m11 * a11;
        a00 = n00; a01 = n01; a10 = n10; a11 = n11;
    }

    k_states_prep<<<2304, 256, 0, stream>>>(u, q0off, p0off, q0on, p0on, b2,
                                            W1, z, b1, Qall, W1qT, cvec, out,
                                            out + 4 * BB,
                                            (float)a00, (float)a01, (float)a10, (float)a11);
    k_gemm<<<512, 256, 0, stream>>>(Qall, W1qT, cvec, W2, out);
}